// Round 13
// baseline (329.597 us; speedup 1.0000x reference)
//
#include <hip/hip_runtime.h>

// ---------------------------------------------------------------------------
// GCN block: 3x (MFMA bf16 GEMM -> degree-normalized aggregate), resid, relu.
// 9 dispatches: memset(cursors) | scatter(fixed-CAP buckets, CHUNK=2048) |
//   sort(+pad,+dinv,+rp2) | gemm1 | agg1 | gemm2 | agg2 | gemm3 | agg3
// R12 profile: scatter was 196 blocks -> 46us latency-bound (6.9% occ);
//   CHUNK 8192->2048 gives 782 blocks. Aggs: 4 nodes/wave -> 64 outstanding
//   gather loads (2x R11 MLP), col fetch uses all 64 lanes.
// Standing lessons: R10 no barrier-coupled gather fusion; R9 dinv in GEMM
// epilogue only; R8 no coop phase fusion; R11 x16 padding + sentinel row N.
// ---------------------------------------------------------------------------

#define LB 8
#define BKN 256
#define CHUNK 2048
#define CAP 8192                   // packed slots per bucket (mean fill 4092)
#define CAPCOL (CAP + BKN * 15)    // padded col region per bucket

typedef unsigned short ushort_t;
typedef __attribute__((ext_vector_type(8))) short bf16x8;
typedef __attribute__((ext_vector_type(4))) float f32x4;

__device__ __forceinline__ unsigned f2bf(float f) {
    unsigned u = __builtin_bit_cast(unsigned, f);
    return (u + 0x7FFFu + ((u >> 16) & 1u)) >> 16;   // RNE
}
__device__ __forceinline__ float bf2f(ushort_t h) {
    unsigned u = ((unsigned)h) << 16;
    return __builtin_bit_cast(float, u);
}

// per-block int64-vs-int32 probe (sampled; same result in every block)
__device__ int detect_f64(const int* ei, int E, int* sflag) {
    if (threadIdx.x == 0) *sflag = 0;
    __syncthreads();
    const unsigned* raw = (const unsigned*)ei;
    int dwords = min(2 * E, 1024);
    int any = 0;
    for (int i = threadIdx.x; i < dwords; i += blockDim.x)
        if ((i & 1) && raw[i]) any = 1;
    if (any) atomicOr(sflag, 1);
    __syncthreads();
    return !*sflag;   // all sampled high words zero => int64
}

// ---- scatter: partition edges into fixed-CAP bucket regions ---------------
// packed[b*CAP + cursor] = (src<<8 | dst&255); cursor is RELATIVE (0-init).
__global__ __launch_bounds__(256) void k_scatter(
        const int* __restrict__ ei, int E,
        int* __restrict__ bucketCursor, unsigned int* __restrict__ packed) {
    __shared__ int hist[512];
    __shared__ int base[512];
    __shared__ int sflag;
    int f64 = detect_f64(ei, E, &sflag);
    int b0 = blockIdx.x * CHUNK;
    int n = min(CHUNK, E - b0);
    for (int i = threadIdx.x; i < 512; i += 256) hist[i] = 0;
    __syncthreads();
    for (int i = threadIdx.x; i < n; i += 256) {
        int e = b0 + i;
        int d = f64 ? ei[2 * (E + e)] : ei[E + e];
        atomicAdd(&hist[d >> LB], 1);
    }
    __syncthreads();
    for (int i = threadIdx.x; i < 512; i += 256) {
        int c = hist[i];
        base[i] = c ? atomicAdd(&bucketCursor[i], c) : 0;
        hist[i] = 0;
    }
    __syncthreads();
    for (int i = threadIdx.x; i < n; i += 256) {
        int e = b0 + i;
        int d = f64 ? ei[2 * (E + e)] : ei[E + e];
        int s = f64 ? ei[2 * e] : ei[e];
        int bk = d >> LB;
        int pos = bk * CAP + base[bk] + atomicAdd(&hist[bk], 1);
        packed[pos] = ((unsigned)s << LB) | (unsigned)(d & (BKN - 1));
    }
}

// ---- per-bucket counting sort -> padded CSR col[], rp2, dinv --------------
// Bucket b's packed region: [b*CAP, b*CAP + cnt) with cnt = bucketCursor[b].
// Node segments padded to x16 with sentinel index N; hs row N zeroed here.
__global__ __launch_bounds__(256) void k_sort(
        const unsigned int* __restrict__ packed, const int* __restrict__ bucketCursor,
        int* __restrict__ col, int2* __restrict__ rp2, float* __restrict__ dinv,
        ushort_t* __restrict__ hs, int N) {
    __shared__ int hist[BKN];
    __shared__ int s[BKN];
    __shared__ int cur[BKN];
    int tid = threadIdx.x;
    int b = blockIdx.x;
    int start = b * CAP;
    int end = start + bucketCursor[b];
    hist[tid] = 0;
    __syncthreads();
    for (int e = start + tid; e < end; e += 256)
        atomicAdd(&hist[packed[e] & (BKN - 1)], 1);
    __syncthreads();
    int v = hist[tid];
    int pv = (v + 15) & ~15;            // padded length
    s[tid] = pv;
    __syncthreads();
    for (int off = 1; off < 256; off <<= 1) {
        int x = (tid >= off) ? s[tid - off] : 0;
        __syncthreads();
        if (tid >= off) s[tid] += x;
        __syncthreads();
    }
    int excl = s[tid] - pv;
    int st = b * CAPCOL + excl;         // padded col base, buckets disjoint
    cur[tid] = st;
    int node = (b << LB) + tid;
    if (node < N) {
        rp2[node] = make_int2(st, st + pv);
        dinv[node] = rsqrtf((float)(v + 1));   // +1 self loop
        for (int i = v; i < pv; i++) col[st + i] = N;   // sentinel padding
    }
    if (b == 0 && tid < 64) hs[(size_t)N * 64 + tid] = 0;   // zero row N
    __syncthreads();
    for (int e = start + tid; e < end; e += 256) {
        unsigned pvk = packed[e];
        int pos = atomicAdd(&cur[pvk & (BKN - 1)], 1);
        col[pos] = (int)(pvk >> LB);
    }
}

// ---- gemm1: (N x 128) @ (128 x 64), f32 in, dinv-scaled, bf16 out ---------
__global__ __launch_bounds__(256) void k_gemm1(
        const float* __restrict__ A, const float* __restrict__ W,
        const float* __restrict__ dinv, ushort_t* __restrict__ out, int nrows) {
    const int K = 128;
    __shared__ ushort_t sWT[64 * (K + 8)];
    int tid = threadIdx.x;
    for (int i = tid; i < K * 64; i += 256) {
        int n = i & 63, k = i >> 6;
        sWT[n * (K + 8) + k] = (ushort_t)f2bf(W[i]);
    }
    __syncthreads();
    int wave = tid >> 6, lane = tid & 63;
    int quad = lane >> 4, l16 = lane & 15;
    int rowBase = blockIdx.x * 128 + wave * 32;
    f32x4 acc[2][4];
#pragma unroll
    for (int r = 0; r < 2; r++)
#pragma unroll
        for (int c = 0; c < 4; c++) acc[r][c] = (f32x4){0.f, 0.f, 0.f, 0.f};
#pragma unroll
    for (int chunk = 0; chunk < K / 32; chunk++) {
        bf16x8 afr[2];
#pragma unroll
        for (int r = 0; r < 2; r++) {
            int row = rowBase + r * 16 + l16;
            if (row >= nrows) row = nrows - 1;
            const float* ap = A + (size_t)row * K + chunk * 32 + quad * 8;
            float4 v0 = *(const float4*)ap;
            float4 v1 = *(const float4*)(ap + 4);
            bf16x8 a;
            a[0] = (short)f2bf(v0.x); a[1] = (short)f2bf(v0.y);
            a[2] = (short)f2bf(v0.z); a[3] = (short)f2bf(v0.w);
            a[4] = (short)f2bf(v1.x); a[5] = (short)f2bf(v1.y);
            a[6] = (short)f2bf(v1.z); a[7] = (short)f2bf(v1.w);
            afr[r] = a;
        }
#pragma unroll
        for (int c = 0; c < 4; c++) {
            bf16x8 bfr = __builtin_bit_cast(
                bf16x8,
                *(const uint4*)&sWT[(c * 16 + l16) * (K + 8) + chunk * 32 + quad * 8]);
#pragma unroll
            for (int r = 0; r < 2; r++)
                acc[r][c] = __builtin_amdgcn_mfma_f32_16x16x32_bf16(
                    afr[r], bfr, acc[r][c], 0, 0, 0);
        }
    }
#pragma unroll
    for (int r = 0; r < 2; r++)
#pragma unroll
        for (int i = 0; i < 4; i++) {
            int row = rowBase + r * 16 + quad * 4 + i;
            if (row < nrows) {
                float sc = dinv[row];
#pragma unroll
                for (int c = 0; c < 4; c++)
                    out[(size_t)row * 64 + c * 16 + l16] =
                        (ushort_t)f2bf(acc[r][c][i] * sc);
            }
        }
}

// ---- gemm64: (N x 64) @ (64 x 64), bf16 in, dinv-scaled, bf16 out ---------
__global__ __launch_bounds__(256) void k_gemm64(
        const ushort_t* __restrict__ A, const float* __restrict__ W,
        const float* __restrict__ dinv, ushort_t* __restrict__ out, int nrows) {
    const int K = 64;
    __shared__ ushort_t sWT[64 * (K + 8)];
    int tid = threadIdx.x;
    for (int i = tid; i < K * 64; i += 256) {
        int n = i & 63, k = i >> 6;
        sWT[n * (K + 8) + k] = (ushort_t)f2bf(W[i]);
    }
    __syncthreads();
    int wave = tid >> 6, lane = tid & 63;
    int quad = lane >> 4, l16 = lane & 15;
    int rowBase = blockIdx.x * 128 + wave * 32;
    f32x4 acc[2][4];
#pragma unroll
    for (int r = 0; r < 2; r++)
#pragma unroll
        for (int c = 0; c < 4; c++) acc[r][c] = (f32x4){0.f, 0.f, 0.f, 0.f};
#pragma unroll
    for (int chunk = 0; chunk < K / 32; chunk++) {
        bf16x8 afr[2];
#pragma unroll
        for (int r = 0; r < 2; r++) {
            int row = rowBase + r * 16 + l16;
            if (row >= nrows) row = nrows - 1;
            const ushort_t* ap = A + (size_t)row * K + chunk * 32 + quad * 8;
            afr[r] = __builtin_bit_cast(bf16x8, *(const uint4*)ap);
        }
#pragma unroll
        for (int c = 0; c < 4; c++) {
            bf16x8 bfr = __builtin_bit_cast(
                bf16x8,
                *(const uint4*)&sWT[(c * 16 + l16) * (K + 8) + chunk * 32 + quad * 8]);
#pragma unroll
            for (int r = 0; r < 2; r++)
                acc[r][c] = __builtin_amdgcn_mfma_f32_16x16x32_bf16(
                    afr[r], bfr, acc[r][c], 0, 0, 0);
        }
    }
#pragma unroll
    for (int r = 0; r < 2; r++)
#pragma unroll
        for (int i = 0; i < 4; i++) {
            int row = rowBase + r * 16 + quad * 4 + i;
            if (row < nrows) {
                float sc = dinv[row];
#pragma unroll
                for (int c = 0; c < 4; c++)
                    out[(size_t)row * 64 + c * 16 + l16] =
                        (ushort_t)f2bf(acc[r][c][i] * sc);
            }
        }
}

// ---- aggregation: FOUR nodes per wave, lane = feature column --------------
// Segments padded to x16 (sentinel N -> zero row). One col load fetches 16
// indices for each of 4 nodes (lane>>4 = node, lane&15 = slot) -> up to 64
// outstanding gather loads per wave. Uniform branches only.
template <int RELU, int F32OUT>
__global__ __launch_bounds__(256) void k_agg4x(
        const ushort_t* __restrict__ hs, const float* __restrict__ dinv,
        const float* __restrict__ bias, const int* __restrict__ col,
        const int2* __restrict__ rp2, const ushort_t* __restrict__ residb,
        float* __restrict__ outf, ushort_t* __restrict__ outb, int n) {
    int gw = (blockIdx.x * blockDim.x + threadIdx.x) >> 6;
    int lane = threadIdx.x & 63;
    int node0 = gw << 2;
    if (node0 >= n) return;
    int node1 = node0 + 1, node2 = node0 + 2, node3 = node0 + 3;
    int2 r0 = rp2[node0];
    int2 r1 = (node1 < n) ? rp2[node1] : make_int2(0, 0);
    int2 r2 = (node2 < n) ? rp2[node2] : make_int2(0, 0);
    int2 r3 = (node3 < n) ? rp2[node3] : make_int2(0, 0);
    float acc0 = bf2f(hs[(node0 << 6) + lane]);   // self loop
    float acc1 = (node1 < n) ? bf2f(hs[(node1 << 6) + lane]) : 0.f;
    float acc2 = (node2 < n) ? bf2f(hs[(node2 << 6) + lane]) : 0.f;
    float acc3 = (node3 < n) ? bf2f(hs[(node3 << 6) + lane]) : 0.f;
    int e0 = r0.x, p0 = r0.y;
    int e1 = r1.x, p1 = r1.y;
    int e2 = r2.x, p2 = r2.y;
    int e3 = r3.x, p3 = r3.y;
    while (e0 < p0 || e1 < p1 || e2 < p2 || e3 < p3) {
        bool a0 = e0 < p0, a1 = e1 < p1, a2 = e2 < p2, a3 = e3 < p3;
        int j = lane >> 4;
        int basee = (j == 0) ? e0 : (j == 1) ? e1 : (j == 2) ? e2 : e3;
        int m = col[basee + (lane & 15)];
        ushort_t u0[16], u1[16], u2[16], u3[16];
        if (a0) {
#pragma unroll
            for (int t = 0; t < 16; t++)
                u0[t] = hs[(__shfl(m, t) << 6) + lane];
        }
        if (a1) {
#pragma unroll
            for (int t = 0; t < 16; t++)
                u1[t] = hs[(__shfl(m, 16 + t) << 6) + lane];
        }
        if (a2) {
#pragma unroll
            for (int t = 0; t < 16; t++)
                u2[t] = hs[(__shfl(m, 32 + t) << 6) + lane];
        }
        if (a3) {
#pragma unroll
            for (int t = 0; t < 16; t++)
                u3[t] = hs[(__shfl(m, 48 + t) << 6) + lane];
        }
        if (a0) {
#pragma unroll
            for (int t = 0; t < 16; t += 4)
                acc0 += bf2f(u0[t]) + bf2f(u0[t + 1]) + bf2f(u0[t + 2]) + bf2f(u0[t + 3]);
            e0 += 16;
        }
        if (a1) {
#pragma unroll
            for (int t = 0; t < 16; t += 4)
                acc1 += bf2f(u1[t]) + bf2f(u1[t + 1]) + bf2f(u1[t + 2]) + bf2f(u1[t + 3]);
            e1 += 16;
        }
        if (a2) {
#pragma unroll
            for (int t = 0; t < 16; t += 4)
                acc2 += bf2f(u2[t]) + bf2f(u2[t + 1]) + bf2f(u2[t + 2]) + bf2f(u2[t + 3]);
            e2 += 16;
        }
        if (a3) {
#pragma unroll
            for (int t = 0; t < 16; t += 4)
                acc3 += bf2f(u3[t]) + bf2f(u3[t + 1]) + bf2f(u3[t + 2]) + bf2f(u3[t + 3]);
            e3 += 16;
        }
    }
    float bv = bias[lane];
#pragma unroll
    for (int k = 0; k < 4; k++) {
        int node = node0 + k;
        if (node >= n) break;
        float a = (k == 0) ? acc0 : (k == 1) ? acc1 : (k == 2) ? acc2 : acc3;
        float o = dinv[node] * a + bv;
        if (RELU) o = fmaxf(o, 0.f);
        if (F32OUT) {
            o += bf2f(residb[(node << 6) + lane]);
            outf[((size_t)node << 6) + lane] = o;
        } else {
            outb[(node << 6) + lane] = (ushort_t)f2bf(o);
        }
    }
}

// ---------------------------------------------------------------------------
extern "C" void kernel_launch(void* const* d_in, const int* in_sizes, int n_in,
                              void* d_out, int out_size, void* d_ws, size_t ws_size,
                              hipStream_t stream) {
    const float* x  = (const float*)d_in[0];
    const int*   ei = (const int*)d_in[1];
    const float* W0 = (const float*)d_in[2];
    const float* b0 = (const float*)d_in[3];
    const float* Ws = (const float*)d_in[4];
    const float* bs = (const float*)d_in[5];
    float* out = (float*)d_out;

    const int N = in_sizes[0] / 128;
    const int E = in_sizes[1] / 2;
    const int B = (N + BKN - 1) >> LB;

    char* p = (char*)d_ws;
    auto carve = [&](size_t bytes) {
        char* r = p;
        p += (bytes + 255) & ~(size_t)255;
        return r;
    };
    int*      bucketCursor = (int*)carve(512 * 4);
    unsigned* packed       = (unsigned*)carve((size_t)B * CAP * 4);
    int*      col          = (int*)carve(((size_t)B * CAPCOL + 64) * 4);
    int2*     rp2          = (int2*)carve((size_t)N * 8);
    float*    dinv         = (float*)carve((size_t)N * 4);
    ushort_t* hs           = (ushort_t*)carve((size_t)(N + 1) * 64 * 2); // +sentinel
    ushort_t* xtb          = (ushort_t*)carve((size_t)N * 64 * 2);
    ushort_t* hb           = (ushort_t*)carve((size_t)N * 64 * 2);

    hipMemsetAsync(bucketCursor, 0, 512 * 4, stream);

    k_scatter<<<(E + CHUNK - 1) / CHUNK, 256, 0, stream>>>(ei, E, bucketCursor, packed);
    k_sort<<<B, 256, 0, stream>>>(packed, bucketCursor, col, rp2, dinv, hs, N);

    int gb = (N + 127) / 128;
    int ablocks = (N + 15) / 16;   // 4 nodes/wave, 4 waves/block

    // layer 1: hs = (x @ W0) * dinv ; agg1 -> xtb (bf16, +b0, no relu)
    k_gemm1<<<gb, 256, 0, stream>>>(x, W0, dinv, hs, N);
    k_agg4x<0, 0><<<ablocks, 256, 0, stream>>>(hs, dinv, b0, col, rp2,
                                               nullptr, nullptr, xtb, N);
    // layer 2: hs = (xtb @ Ws0) * dinv ; agg2 -> hb (bf16, +bs0, relu)
    k_gemm64<<<gb, 256, 0, stream>>>(xtb, Ws, dinv, hs, N);
    k_agg4x<1, 0><<<ablocks, 256, 0, stream>>>(hs, dinv, bs, col, rp2,
                                               nullptr, nullptr, hb, N);
    // layer 3: hs = (hb @ Ws1) * dinv ; agg3 -> out (f32, +bs1, relu, +resid)
    k_gemm64<<<gb, 256, 0, stream>>>(hb, Ws + 64 * 64, dinv, hs, N);
    k_agg4x<1, 1><<<ablocks, 256, 0, stream>>>(hs, dinv, bs + 64, col, rp2,
                                               xtb, out, nullptr, N);
}